// Round 8
// baseline (271.116 us; speedup 1.0000x reference)
//
#include <hip/hip_runtime.h>

#define KDIM 4096   // rows of x (= both i and j extents)
#define NDIM 1024   // feature dim
#define ALPHA 0.2f
#define LOG2E 1.4426950408889634f

typedef _Float16 h2    __attribute__((ext_vector_type(2)));
typedef _Float16 f16x8 __attribute__((ext_vector_type(8)));
typedef __attribute__((ext_vector_type(4))) float f32x4;

// P is never materialized: P_ij = max(E1_j*F1_i, E2_j*F2_i)  (select == max:
// the two lrelu branches cross exactly where they're equal, at s1+s2 = 0).
__device__ __align__(16) unsigned short g_xT [(size_t)NDIM * KDIM]; // 8 MB x^T f16
__device__ __align__(16) float          g_s1L[KDIM];
__device__ __align__(16) float          g_s2L[KDIM];
__device__ __align__(16) unsigned short g_E1h[KDIM];   // f16: exp2(s2L_j)
__device__ __align__(16) unsigned short g_E2h[KDIM];   // f16: exp2(ALPHA*s2L_j)
__device__ __align__(16) unsigned int   g_Fh [KDIM];   // packed f16 (F1_i, F2_i)
__device__ __align__(16) float          g_rZ [KDIM];
__device__ unsigned int g_tick = 0;    // grid-barrier ticket (monotone across launches)

__device__ __forceinline__ unsigned short f2h(float f){
  _Float16 h = (_Float16)f;
  return *(unsigned short*)&h;
}

// Device-scope ticket barrier: 256 co-resident blocks (grid==256, 1 block/CU-ish;
// even at 2 blocks/CU capacity all 256 are resident => no deadlock).
__device__ __forceinline__ void gbar(int tid){
  __syncthreads();
  __threadfence();                                  // agent-scope release of prior stores
  if (tid == 0){
    unsigned t = __hip_atomic_fetch_add(&g_tick, 1u, __ATOMIC_ACQ_REL, __HIP_MEMORY_SCOPE_AGENT);
    const unsigned target = (t / 256u + 1u) * 256u;
    while (__hip_atomic_load(&g_tick, __ATOMIC_ACQUIRE, __HIP_MEMORY_SCOPE_AGENT) < target)
      __builtin_amdgcn_s_sleep(2);
  }
  __syncthreads();
  __threadfence();                                  // acquire side for all threads
}

__global__ __launch_bounds__(512, 2) void k_fused(const float* __restrict__ x,
                                                  const float* __restrict__ w,
                                                  float* __restrict__ out){
  __shared__ __align__(16) unsigned char smem[65536];
  const int tid  = threadIdx.x;
  const int wv   = tid >> 6, lane = tid & 63;
  const int quad = lane >> 4, l15 = lane & 15;
  const int b    = blockIdx.x;

  // ================= P0a: s1L/s2L dots (16 rows/block, 2 rows/wave) ========
  #pragma unroll
  for (int rr = 0; rr < 2; ++rr){
    const int row = b * 16 + wv * 2 + rr;
    const float* xr = x + (size_t)row * NDIM;
    float d1 = 0.f, d2 = 0.f;
    #pragma unroll
    for (int q = 0; q < 4; ++q){
      const int off = q * 256 + lane * 4;
      float4 X  = *(const float4*)(xr + off);
      float4 W1 = *(const float4*)(w + off);
      float4 W2 = *(const float4*)(w + NDIM + off);
      d1 = fmaf(X.x, W1.x, fmaf(X.y, W1.y, fmaf(X.z, W1.z, fmaf(X.w, W1.w, d1))));
      d2 = fmaf(X.x, W2.x, fmaf(X.y, W2.y, fmaf(X.z, W2.z, fmaf(X.w, W2.w, d2))));
    }
    #pragma unroll
    for (int m = 32; m >= 1; m >>= 1){
      d1 += __shfl_xor(d1, m, 64);
      d2 += __shfl_xor(d2, m, 64);
    }
    if (lane == 0){
      g_s1L[row] = d1 * LOG2E;
      g_s2L[row] = d2 * LOG2E;
    }
  }

  // ================= P0b: transpose x -> g_xT (4 64x64 tiles/block) ========
  {
    unsigned short (*T)[80] = (unsigned short(*)[80])smem;   // 10.2 KB
    for (int c = 0; c < 4; ++c){
      const int t = b * 4 + c;
      const int n0t = (t & 15) * 64, j0t = (t >> 4) * 64;
      __syncthreads();
      #pragma unroll
      for (int it = 0; it < 2; ++it){
        const int idx = it * 512 + tid;
        const int r = idx >> 4, c4 = idx & 15;
        float4 v = *(const float4*)(x + (size_t)(j0t + r) * NDIM + n0t + c4 * 4);
        T[c4 * 4 + 0][r] = f2h(v.x);
        T[c4 * 4 + 1][r] = f2h(v.y);
        T[c4 * 4 + 2][r] = f2h(v.z);
        T[c4 * 4 + 3][r] = f2h(v.w);
      }
      __syncthreads();
      {
        const int n = tid >> 3, cb = tid & 7;
        uint4 u = *(const uint4*)&T[n][cb * 8];
        *(uint4*)(g_xT + (size_t)(n0t + n) * KDIM + j0t + cb * 8) = u;
      }
    }
  }

  gbar(tid);

  // ================= P1: m2, F1/F2/rZ per row; E1/E2 per j =================
  {
    float* s2  = (float*)smem;              // 16 KB
    float* red = (float*)(smem + 16384);    // 2 KB
    float mx = -3.0e38f;
    #pragma unroll
    for (int it = 0; it < 2; ++it){
      const int idx = it * 512 + tid;
      float4 v = ((const float4*)g_s2L)[idx];
      ((float4*)s2)[idx] = v;
      mx = fmaxf(mx, fmaxf(fmaxf(v.x, v.y), fmaxf(v.z, v.w)));
    }
    red[tid] = mx;
    __syncthreads();
    #pragma unroll
    for (int s = 256; s >= 1; s >>= 1){
      if (tid < s) red[tid] = fmaxf(red[tid], red[tid + s]);
      __syncthreads();
    }
    const float m2 = red[0];

    #pragma unroll
    for (int rr = 0; rr < 2; ++rr){
      const int row = b * 16 + wv * 2 + rr;
      const float s1 = g_s1L[row];
      const float t  = s1 + m2;
      const float mL = fmaxf(t, ALPHA * t);
      const float F1 = __builtin_amdgcn_exp2f(s1 - mL);
      const float F2 = __builtin_amdgcn_exp2f(fmaf(ALPHA, s1, -mL));
      float z = 0.f;
      #pragma unroll 8
      for (int c = 0; c < 64; ++c){
        const float s = s2[c * 64 + lane];
        z += fmaxf(__builtin_amdgcn_exp2f(s) * F1,
                   __builtin_amdgcn_exp2f(ALPHA * s) * F2);
      }
      #pragma unroll
      for (int m = 32; m >= 1; m >>= 1) z += __shfl_xor(z, m, 64);
      if (lane == 0){
        g_rZ[row] = 1.0f / z;
        g_Fh[row] = (unsigned int)f2h(F1) | ((unsigned int)f2h(F2) << 16);
      }
    }
    if (tid < 16){
      const int j = b * 16 + tid;
      const float s = g_s2L[j];
      g_E1h[j] = f2h(__builtin_amdgcn_exp2f(s));
      g_E2h[j] = f2h(__builtin_amdgcn_exp2f(ALPHA * s));
    }
  }

  gbar(tid);

  // ================= P2: h = (P @ x) * rZ ==================================
  // 128m x 128n block tile; 8 waves as 2m x 4n (wave 64m x 32n: mf=4, nf=2).
  // BK=128 double-buffered B in LDS (2 x 32 KB); E in register dbuf.
  unsigned short* Bb0 = (unsigned short*)smem;            // 32 KB
  unsigned short* Bb1 = (unsigned short*)(smem + 32768);  // 32 KB
  const int n0   = (b & 7) * 128;          // XCD-affine n-slice
  const int m0b  = (b >> 3) * 128;
  const int moff = (wv & 1) * 64;
  const int noff = (wv >> 1) * 32;
  const int srow = lane >> 4;              // 0..3 (4 n-rows per 1KB glds chunk)
  const int sb16 = lane & 15;

  h2 F1s[4], F2s[4];
  #pragma unroll
  for (int mf = 0; mf < 4; ++mf){
    const unsigned int fb = g_Fh[m0b + moff + mf * 16 + l15];
    const h2 fp = *(const h2*)&fb;
    F1s[mf] = (h2){fp.x, fp.x};
    F2s[mf] = (h2){fp.y, fp.y};
  }

  f32x4 acc[4][2] = {};

  auto stage = [&](int kt, unsigned short* buf){
    #pragma unroll
    for (int c = 0; c < 4; ++c){
      const int ca = wv * 4 + c;                  // chunk 0..31, 4 n-rows each
      const int r  = ca * 4 + srow;
      const int sblk = sb16 ^ (r & 7);            // XOR bank swizzle
      const unsigned short* gp = g_xT + (size_t)(n0 + r) * KDIM + kt * 128 + sblk * 8;
      __builtin_amdgcn_global_load_lds((const __attribute__((address_space(1))) void*)gp,
          (__attribute__((address_space(3))) void*)(buf + ca * 512), 16, 0, 0);
    }
  };
  auto ldE = [&](int kt, uint4* e1, uint4* e2){
    #pragma unroll
    for (int ks = 0; ks < 4; ++ks){
      const int kb = kt * 128 + ks * 32 + quad * 8;
      e1[ks] = *(const uint4*)(g_E1h + kb);
      e2[ks] = *(const uint4*)(g_E2h + kb);
    }
  };
  auto compute = [&](const uint4* e1, const uint4* e2, const unsigned short* buf){
    #pragma unroll
    for (int ks = 0; ks < 4; ++ks){
      const h2* E1p = (const h2*)&e1[ks];
      const h2* E2p = (const h2*)&e2[ks];
      union { h2 h[4]; f16x8 v; } af[4];
      #pragma unroll
      for (int jp = 0; jp < 4; ++jp)
        #pragma unroll
        for (int mf = 0; mf < 4; ++mf)
          af[mf].h[jp] = __builtin_elementwise_max(E1p[jp] * F1s[mf],
                                                   E2p[jp] * F2s[mf]);
      #pragma unroll
      for (int nf = 0; nf < 2; ++nf){
        const int n = noff + nf * 16 + l15;
        const int lbq = ((ks << 2) + quad) ^ (n & 7);
        const f16x8 bfr = *(const f16x8*)((const char*)buf + n * 256 + lbq * 16);
        #pragma unroll
        for (int mf = 0; mf < 4; ++mf)
          acc[mf][nf] = __builtin_amdgcn_mfma_f32_16x16x32_f16(af[mf].v, bfr, acc[mf][nf], 0, 0, 0);
      }
    }
  };

  uint4 e1a[4], e2a[4], e1b[4], e2b[4];
  stage(0, Bb0);
  ldE(0, e1a, e2a);
  for (int kt2 = 0; kt2 < 16; ++kt2){
    const int kta = kt2 * 2;
    __syncthreads();
    { stage(kta + 1, Bb1); ldE(kta + 1, e1b, e2b); }    // prefetch overlaps compute
    compute(e1a, e2a, Bb0);
    __syncthreads();
    if (kt2 < 15){ stage(kta + 2, Bb0); ldE(kta + 2, e1a, e2a); }
    compute(e1b, e2b, Bb1);
  }

  // epilogue: scale by 1/Z_i. C/D layout: col=lane&15, row=quad*4+reg.
  #pragma unroll
  for (int mf = 0; mf < 4; ++mf){
    #pragma unroll
    for (int r = 0; r < 4; ++r){
      const int row = m0b + moff + mf * 16 + quad * 4 + r;
      const float rz = g_rZ[row];
      #pragma unroll
      for (int nf = 0; nf < 2; ++nf)
        out[(size_t)row * NDIM + n0 + noff + nf * 16 + l15] = acc[mf][nf][r] * rz;
    }
  }
}

extern "C" void kernel_launch(void* const* d_in, const int* in_sizes, int n_in,
                              void* d_out, int out_size, void* d_ws, size_t ws_size,
                              hipStream_t stream){
  const float* x = (const float*)d_in[0];   // f32 (4096x1024)
  const float* w = (const float*)d_in[1];   // f32 (2048)
  float* out = (float*)d_out;               // f32 (4096x1024)
  (void)in_sizes; (void)n_in; (void)out_size; (void)d_ws; (void)ws_size;

  k_fused<<<dim3(256), dim3(512), 0, stream>>>(x, w, out);
}

// Round 9
// 154.634 us; speedup vs baseline: 1.7533x; 1.7533x over previous
//
#include <hip/hip_runtime.h>

#define KDIM 4096   // rows of x (= both i and j extents)
#define NDIM 1024   // feature dim
#define ALPHA 0.2f
#define LOG2E 1.4426950408889634f

typedef _Float16 h2    __attribute__((ext_vector_type(2)));
typedef _Float16 f16x8 __attribute__((ext_vector_type(8)));
typedef __attribute__((ext_vector_type(4))) float f32x4;

// P is never materialized: P_ij = max(E1_j*F1_i, E2_j*F2_i)  (select == max:
// the two lrelu branches cross exactly where they're equal, at s1+s2 = 0).
__device__ __align__(16) unsigned short g_xT [(size_t)NDIM * KDIM]; // 8 MB x^T f16
__device__ __align__(16) float          g_s1L[KDIM];
__device__ __align__(16) float          g_s2L[KDIM];
__device__ __align__(16) unsigned short g_E1h[KDIM];   // f16: exp2(s2L_j)
__device__ __align__(16) unsigned short g_E2h[KDIM];   // f16: exp2(ALPHA*s2L_j)
__device__ __align__(16) unsigned int   g_Fh [KDIM];   // packed f16 (F1_i, F2_i)
__device__ __align__(16) float          g_rZ [KDIM];

__device__ __forceinline__ unsigned short f2h(float f){
  _Float16 h = (_Float16)f;
  return *(unsigned short*)&h;
}

// ---- kernel 1: s1L/s2L = (x @ w1, x @ w2) * log2(e).  One wave per row. ----
__global__ __launch_bounds__(256) void k_dots(const float* __restrict__ x,
                                              const float* __restrict__ w){
  const int wid = threadIdx.x >> 6, lane = threadIdx.x & 63;
  const int row = blockIdx.x * 4 + wid;
  const float* xr = x + (size_t)row * NDIM;
  float d1 = 0.f, d2 = 0.f;
  #pragma unroll
  for (int q = 0; q < 4; ++q){
    const int off = q * 256 + lane * 4;
    float4 X  = *(const float4*)(xr + off);
    float4 W1 = *(const float4*)(w + off);
    float4 W2 = *(const float4*)(w + NDIM + off);
    d1 = fmaf(X.x, W1.x, fmaf(X.y, W1.y, fmaf(X.z, W1.z, fmaf(X.w, W1.w, d1))));
    d2 = fmaf(X.x, W2.x, fmaf(X.y, W2.y, fmaf(X.z, W2.z, fmaf(X.w, W2.w, d2))));
  }
  #pragma unroll
  for (int m = 32; m >= 1; m >>= 1){
    d1 += __shfl_xor(d1, m, 64);
    d2 += __shfl_xor(d2, m, 64);
  }
  if (lane == 0){
    g_s1L[row] = d1 * LOG2E;
    g_s2L[row] = d2 * LOG2E;
  }
}

// ---- kernel 2: fused transpose-tile + Z/F/E. 1024 blocks x 256 thr. ----
// Phase A: transpose one 64x64 tile of x -> g_xT (f16).
// Phase B: m2 = max(s2L); rows bid*4..+3: F1/F2/rZ; E1h/E2h for j=bid*4..+3.
__global__ __launch_bounds__(256) void k_tzf(const float* __restrict__ x){
  __shared__ __align__(16) unsigned char smem[17408];
  const int tid = threadIdx.x;
  const int bid = blockIdx.x;

  { // Phase A: transpose tile (n0t, j0t)
    unsigned short (*T)[80] = (unsigned short(*)[80])smem;   // 10.2 KB
    const int n0t = (bid & 15) * 64, j0t = (bid >> 4) * 64;
    #pragma unroll
    for (int it = 0; it < 4; ++it){
      const int idx = it * 256 + tid;
      const int r = idx >> 4, c4 = idx & 15;
      float4 v = *(const float4*)(x + (size_t)(j0t + r) * NDIM + n0t + c4 * 4);
      T[c4 * 4 + 0][r] = f2h(v.x);
      T[c4 * 4 + 1][r] = f2h(v.y);
      T[c4 * 4 + 2][r] = f2h(v.z);
      T[c4 * 4 + 3][r] = f2h(v.w);
    }
    __syncthreads();
    #pragma unroll
    for (int it = 0; it < 2; ++it){
      const int idx = it * 256 + tid;
      const int n = idx >> 3, cb = idx & 7;
      uint4 u = *(const uint4*)&T[n][cb * 8];
      *(uint4*)(g_xT + (size_t)(n0t + n) * KDIM + j0t + cb * 8) = u;
    }
    __syncthreads();   // before smem reuse
  }

  { // Phase B
    float* s2  = (float*)smem;              // 16 KB
    float* red = (float*)(smem + 16384);    // 1 KB
    float mx = -3.0e38f;
    {
      int i = tid * 4;
      #pragma unroll
      for (int c = 0; c < 4; ++c, i += 1024){
        float4 v = *(const float4*)&g_s2L[i];
        *(float4*)&s2[i] = v;
        mx = fmaxf(mx, fmaxf(fmaxf(v.x, v.y), fmaxf(v.z, v.w)));
      }
    }
    red[tid] = mx;
    __syncthreads();
    #pragma unroll
    for (int s = 128; s >= 1; s >>= 1){
      if (tid < s) red[tid] = fmaxf(red[tid], red[tid + s]);
      __syncthreads();
    }
    const float m2 = red[0];

    const int wid = tid >> 6, lane = tid & 63;
    const int row = bid * 4 + wid;
    const float s1 = g_s1L[row];
    const float t  = s1 + m2;
    const float mL = fmaxf(t, ALPHA * t);          // lrelu in log2 space
    const float F1 = __builtin_amdgcn_exp2f(s1 - mL);
    const float F2 = __builtin_amdgcn_exp2f(fmaf(ALPHA, s1, -mL));
    float z = 0.f;
    #pragma unroll 8
    for (int c = 0; c < 64; ++c){
      const float s = s2[c * 64 + lane];
      z += fmaxf(__builtin_amdgcn_exp2f(s) * F1,
                 __builtin_amdgcn_exp2f(ALPHA * s) * F2);
    }
    #pragma unroll
    for (int m = 32; m >= 1; m >>= 1) z += __shfl_xor(z, m, 64);
    if (lane == 0){
      g_rZ[row] = 1.0f / z;
      g_Fh[row] = (unsigned int)f2h(F1) | ((unsigned int)f2h(F2) << 16);
    }
    if (tid < 4){
      const int j = bid * 4 + tid;
      const float s = s2[j];
      g_E1h[j] = f2h(__builtin_amdgcn_exp2f(s));
      g_E2h[j] = f2h(__builtin_amdgcn_exp2f(ALPHA * s));
    }
  }
}

// ---- kernel 3: h = (P @ x) * rZ.  NO LDS, NO barriers. ----
// Wave-tile 64m x 32n (mf=4, nf=2); 256-thr block = 4 waves as 2m x 2n
// (block 128m x 64n); grid 512 = 32m x 16n, n-col = bid&15 so XCD (bid&7)
// serves n-cols {c, c+8}: its 1 MB xT slice + E stay L2-resident.
// B frags are loaded straight from L2 into registers (16 B contiguous k per
// lane), software-pipelined one 32k-step ahead. A is generated in-register
// from E (per-k) and F (per-row) as packed-f16 mul/mul/max.
__global__ __launch_bounds__(256) void k_gemm(float* __restrict__ out){
  const int tid  = threadIdx.x;
  const int wv   = tid >> 6, lane = tid & 63;
  const int quad = lane >> 4, l15 = lane & 15;
  const int bid  = blockIdx.x;
  const int n0 = (bid & 15) * 64 + (wv & 1) * 32;   // wave n-base
  const int m0 = (bid >> 4) * 128 + (wv >> 1) * 64; // wave m-base

  // Per-lane F splats for the 4 m-frags (rows m0 + mf*16 + l15)
  h2 F1s[4], F2s[4];
  #pragma unroll
  for (int mf = 0; mf < 4; ++mf){
    const unsigned int fb = g_Fh[m0 + mf * 16 + l15];
    const h2 fp = *(const h2*)&fb;
    F1s[mf] = (h2){fp.x, fp.x};
    F2s[mf] = (h2){fp.y, fp.y};
  }

  // Row pointers: this lane's B rows (nf=0,1) and E chunk (quad-uniform).
  const unsigned short* bp0 = g_xT + (size_t)(n0 + l15) * KDIM + quad * 8;
  const unsigned short* bp1 = g_xT + (size_t)(n0 + 16 + l15) * KDIM + quad * 8;
  const unsigned short* e1p = g_E1h + quad * 8;
  const unsigned short* e2p = g_E2h + quad * 8;

  f32x4 acc[4][2] = {};
  uint4 Bf[2][2], E1f[2], E2f[2];   // [parity][nf] register pipeline

  auto ld = [&](int kt, int p){
    const int o = kt * 32;          // elements
    Bf[p][0] = *(const uint4*)(bp0 + o);
    Bf[p][1] = *(const uint4*)(bp1 + o);
    E1f[p]   = *(const uint4*)(e1p + o);
    E2f[p]   = *(const uint4*)(e2p + o);
  };
  auto step = [&](int p){
    union { h2 h[4]; f16x8 v; } af[4];
    const h2* E1p = (const h2*)&E1f[p];
    const h2* E2p = (const h2*)&E2f[p];
    #pragma unroll
    for (int jp = 0; jp < 4; ++jp)
      #pragma unroll
      for (int mf = 0; mf < 4; ++mf)
        af[mf].h[jp] = __builtin_elementwise_max(E1p[jp] * F1s[mf],
                                                 E2p[jp] * F2s[mf]);
    #pragma unroll
    for (int nf = 0; nf < 2; ++nf){
      union { uint4 u; f16x8 v; } bb; bb.u = Bf[p][nf];
      #pragma unroll
      for (int mf = 0; mf < 4; ++mf)
        acc[mf][nf] = __builtin_amdgcn_mfma_f32_16x16x32_f16(af[mf].v, bb.v, acc[mf][nf], 0, 0, 0);
    }
  };

  ld(0, 0);
  for (int kt2 = 0; kt2 < 64; ++kt2){
    const int kA = kt2 * 2;
    ld(kA + 1, 1);                 // prefetch overlaps step A
    step(0);
    if (kt2 < 63) ld(kA + 2, 0);   // prefetch overlaps step B
    step(1);
  }

  // epilogue: scale by 1/Z_i. C/D layout: col=lane&15, row=quad*4+reg.
  #pragma unroll
  for (int mf = 0; mf < 4; ++mf){
    #pragma unroll
    for (int r = 0; r < 4; ++r){
      const int row = m0 + mf * 16 + quad * 4 + r;
      const float rz = g_rZ[row];
      #pragma unroll
      for (int nf = 0; nf < 2; ++nf)
        out[(size_t)row * NDIM + n0 + nf * 16 + l15] = acc[mf][nf][r] * rz;
    }
  }
}

extern "C" void kernel_launch(void* const* d_in, const int* in_sizes, int n_in,
                              void* d_out, int out_size, void* d_ws, size_t ws_size,
                              hipStream_t stream){
  const float* x = (const float*)d_in[0];   // f32 (4096x1024)
  const float* w = (const float*)d_in[1];   // f32 (2048)
  float* out = (float*)d_out;               // f32 (4096x1024)
  (void)in_sizes; (void)n_in; (void)out_size; (void)d_ws; (void)ws_size;

  k_dots<<<dim3(1024), dim3(256), 0, stream>>>(x, w);
  k_tzf <<<dim3(1024), dim3(256), 0, stream>>>(x);
  k_gemm<<<dim3(512),  dim3(256), 0, stream>>>(out);
}